// Round 13
// baseline (379.889 us; speedup 1.0000x reference)
//
#include <hip/hip_runtime.h>

#define B 16384
#define C 4
#define M 512
#define D 512
#define NSEG 64   // B/256 candidate segments
#define QSCALE 16777216.0f   // 2^24 fixed-point scale for deterministic atomics
#define BCAP 1024            // boundary-bin collection capacity

// normalize -0.0 -> +0.0 so positive-float bit ordering is valid
__device__ inline unsigned posbits(float e)
{
    unsigned b = __float_as_uint(e);
    return (b == 0x80000000u) ? 0u : b;
}
// monotone (non-strict) 24-bit scaled key for binning; ent in [0, ln4]
__device__ inline unsigned skOfBits(unsigned bits)
{
    float e = __uint_as_float(bits);
    float s = fminf(fmaxf(e * 12000000.0f, 0.0f), 16777215.0f);
    return (unsigned)s;
}

// ---------------- K1: stats + segmented candidate build --------------------
__global__ __launch_bounds__(256) void k1_stats(
    const float* __restrict__ logits,
    const float* __restrict__ ent_memo,
    float* __restrict__ out,
    int* __restrict__ blockCnt,
    uint2* __restrict__ candList,
    unsigned long long* __restrict__ SQ)
{
    __shared__ int wscan[4];
    const int tid = threadIdx.x, blk = blockIdx.x;
    const int gid = blk * 256 + tid;

    float4 l = *reinterpret_cast<const float4*>(logits + (size_t)gid * 4);
    float m = l.x; int idx = 0;
    if (l.y > m) { m = l.y; idx = 1; }
    if (l.z > m) { m = l.z; idx = 2; }
    if (l.w > m) { m = l.w; idx = 3; }
    float e0 = expf(l.x - m), e1 = expf(l.y - m), e2 = expf(l.z - m), e3 = expf(l.w - m);
    float s = e0 + e1 + e2 + e3;
    float inv = 1.0f / s;
    float p0 = e0 * inv, p1 = e1 * inv, p2 = e2 * inv, p3 = e3 * inv;
    float lse = logf(s);
    float ent = -(p0 * (l.x - m - lse) + p1 * (l.y - m - lse)
                + p2 * (l.z - m - lse) + p3 * (l.w - m - lse));
    float4 pr = { p0, p1, p2, p3 };
    *reinterpret_cast<float4*>(out + (size_t)B * 4 + (size_t)gid * 4) = pr;
    out[(size_t)B * 8 + gid] = ent;

    if (gid < C * M) SQ[gid] = 0ULL;

    float amax = ent_memo[(idx << 9) + M - 1];
    bool flag = ent < amax;
    unsigned bits = posbits(ent);

    // block-level compaction (order = b ascending within segment)
    unsigned long long mask = __ballot(flag);
    int lane = tid & 63, wv = tid >> 6;
    int prefix = __popcll(mask & ((1ull << lane) - 1ull));
    if (lane == 0) wscan[wv] = __popcll(mask);
    __syncthreads();
    int base = 0;
    for (int w = 0; w < wv; w++) base += wscan[w];
    if (flag)
        candList[blk * 256 + base + prefix] =
            make_uint2(bits, ((unsigned)idx << 14) | (unsigned)gid);
    if (tid == 0)
        blockCnt[blk] = wscan[0] + wscan[1] + wscan[2] + wscan[3];
}

// ---------------- KT: one-block exact per-label threshold select -----------
__global__ __launch_bounds__(256) void kT_select(
    const int* __restrict__ blockCnt,
    const uint2* __restrict__ candList,
    const float* __restrict__ ent_memo,
    unsigned long long* __restrict__ Tkey)
{
    __shared__ int cnts[NSEG];
    __shared__ unsigned hist[4][256];          // 4 KB
    __shared__ unsigned long long bkeys[BCAP]; // 8 KB
    __shared__ int blabs[BCAP];                // 4 KB
    __shared__ int bnum;
    __shared__ int betaS[4], mremS[4];

    const int tid = threadIdx.x;
    const int lane = tid & 63;

    if (tid < NSEG) cnts[tid] = blockCnt[tid];
    for (int i = tid; i < 1024; i += 256) hist[i >> 8][i & 255] = 0u;
    if (tid == 0) bnum = 0;
    __syncthreads();

    // ---- histogram (wave-aggregated: one LDS atomic per distinct key/wave)
    for (int slot = tid; slot < B; slot += 256) {
        uint2 v = candList[slot];              // unconditional (allocated)
        bool valid = (slot & 255) < cnts[slot >> 8];
        int key = valid ? (int)((((v.y >> 14) & 3) << 8) | (skOfBits(v.x) >> 16)) : -1;
        unsigned long long active = __ballot(valid);
        while (active) {
            int leader = (int)__ffsll((unsigned long long)active) - 1;
            int lkey = __shfl(key, leader, 64);
            unsigned long long match = __ballot(key == lkey);
            if (lane == leader)
                atomicAdd(&hist[lkey >> 8][lkey & 255], (unsigned)__popcll(match));
            active &= ~match;
        }
    }
    for (int i = tid; i < C * M; i += 256) {
        unsigned bits = posbits(ent_memo[i]);
        int key = (int)(((unsigned)(i >> 9) << 8) | (skOfBits(bits) >> 16));
        unsigned long long active = ~0ULL;
        while (active) {
            int leader = (int)__ffsll((unsigned long long)active) - 1;
            int lkey = __shfl(key, leader, 64);
            unsigned long long match = __ballot(key == lkey);
            if (lane == leader)
                atomicAdd(&hist[lkey >> 8][lkey & 255], (unsigned)__popcll(match));
            active &= ~match;
        }
    }
    __syncthreads();

    if (tid < 4) {
        int cum = 0, beta = 255, mr = M;
        for (int bin = 0; bin < 256; bin++) {
            int h = (int)hist[tid][bin];
            if (cum + h >= M) { beta = bin; mr = M - cum; break; }
            cum += h;
        }
        betaS[tid] = beta; mremS[tid] = mr;    // need mr-th smallest in bin beta
        Tkey[tid] = ~0ULL;                     // provisional
    }
    __syncthreads();

    // ---- collect boundary-bin items (full 47-bit keys; unique) ----
    for (int slot = tid; slot < B; slot += 256) {
        uint2 v = candList[slot];
        if ((slot & 255) < cnts[slot >> 8]) {
            int lab = (int)((v.y >> 14) & 3);
            if ((int)(skOfBits(v.x) >> 16) == betaS[lab]) {
                int id = atomicAdd(&bnum, 1);
                if (id < BCAP) {
                    bkeys[id] = ((unsigned long long)v.x << 15)
                              | (unsigned)(512 + (v.y & 0x3FFF));
                    blabs[id] = lab;
                }
            }
        }
    }
    for (int i = tid; i < C * M; i += 256) {
        unsigned bits = posbits(ent_memo[i]);
        int lab = i >> 9;
        if ((int)(skOfBits(bits) >> 16) == betaS[lab]) {
            int id = atomicAdd(&bnum, 1);
            if (id < BCAP) {
                bkeys[id] = ((unsigned long long)bits << 15) | (unsigned)(i & (M - 1));
                blabs[id] = lab;
            }
        }
    }
    __syncthreads();
    int nb = bnum < BCAP ? bnum : BCAP;
    for (int t = tid; t < nb; t += 256) {
        unsigned long long k = bkeys[t]; int l = blabs[t];
        int r = 0;
        for (int j = 0; j < nb; j++)
            if (blabs[j] == l && bkeys[j] < k) r++;
        if (r == mremS[l] - 1) Tkey[l] = k;    // unique writer per label
    }
}

// ---------------- KB: flag-masked dense accumulate -> SQ (int64 fx) --------
// blocks 0..511: batch, seg = x>>3, colchunk q = x&7 (64 cols).
// blocks 512..575: memo rowgroups. Deterministic int64 fixed-point atomics.
__global__ __launch_bounds__(256) void kB_acc(
    const int* __restrict__ blockCnt,
    const uint2* __restrict__ candList,
    const float* __restrict__ ent_memo,
    const unsigned long long* __restrict__ Tkey,
    const float* __restrict__ text_memo,
    const float* __restrict__ text_embeds,
    unsigned long long* __restrict__ SQ)
{
    __shared__ int meta[256];
    __shared__ unsigned long long TkeyS[4];
    const int x = blockIdx.x, tid = threadIdx.x;
    const int col0 = (x & 7) << 6;
    const int lane = tid & 63, sg = tid >> 6;

    if (tid < 4) TkeyS[tid] = Tkey[tid];

    if (x < 512) {
        const int seg = x >> 3;
        const int cnt = blockCnt[seg];
        uint2 v = candList[(seg << 8) + tid];
        __syncthreads();
        {
            int lab = (int)((v.y >> 14) & 3);
            unsigned long long key = ((unsigned long long)v.x << 15)
                                   | (unsigned)(512 + (v.y & 0x3FFF));
            bool kept = (tid < cnt) && (key <= TkeyS[lab]);
            meta[tid] = kept ? (int)((unsigned)lab | 4u | ((v.y & 0x3FFF) << 3)) : 0;
        }
        __syncthreads();
        float a0 = 0.f, a1 = 0.f, a2 = 0.f, a3 = 0.f;
        #pragma unroll 8
        for (int k = 0; k < 64; k++) {
            int slot = (k << 2) | sg;               // wave-uniform
            int mt = meta[slot];
            int bidx = mt >> 3;
            float vv = text_embeds[(size_t)bidx * D + col0 + lane]; // unkept -> row 0 (L2)
            bool kept = (mt & 4) != 0;
            int lb = mt & 3;
            a0 += (kept && lb == 0) ? vv : 0.f;
            a1 += (kept && lb == 1) ? vv : 0.f;
            a2 += (kept && lb == 2) ? vv : 0.f;
            a3 += (kept && lb == 3) ? vv : 0.f;
        }
        __shared__ float red[4][4][64];             // [sg][label][lane]
        red[sg][0][lane] = a0; red[sg][1][lane] = a1;
        red[sg][2][lane] = a2; red[sg][3][lane] = a3;
        __syncthreads();
        float t = ((red[0][sg][lane] + red[1][sg][lane])
                 + red[2][sg][lane]) + red[3][sg][lane];
        long long q = llrintf(t * QSCALE);
        atomicAdd(&SQ[(sg << 9) + col0 + lane], (unsigned long long)q);
    } else {
        const int g = (x - 512) >> 3;               // rowgroup 0..7
        const int c = g >> 1;                       // label
        const int base = g << 8;                    // first global memo row
        {
            int i = base + tid;
            unsigned bits = posbits(ent_memo[i]);
            unsigned long long key = ((unsigned long long)bits << 15)
                                   | (unsigned)(i & (M - 1));
            __syncthreads();
            meta[tid] = (key <= TkeyS[c]) ? 1 : 0;
        }
        __syncthreads();
        float a = 0.f;
        #pragma unroll 8
        for (int k = 0; k < 64; k++) {
            int slot = (k << 2) | sg;
            float vv = text_memo[(size_t)(base + slot) * D + col0 + lane];
            a += meta[slot] ? vv : 0.f;
        }
        __shared__ float redm[4][64];
        redm[sg][lane] = a;
        __syncthreads();
        if (tid < 64) {
            float t = ((redm[0][tid] + redm[1][tid]) + redm[2][tid]) + redm[3][tid];
            long long q = llrintf(t * QSCALE);
            atomicAdd(&SQ[(c << 9) + col0 + tid], (unsigned long long)q);
        }
    }
}

// ---------------- KC: SQ->VGPR S + GEMV + combines + softmaxes -------------
__global__ __launch_bounds__(256) void kC_cosin(
    const unsigned long long* __restrict__ SQ,
    const float* __restrict__ text_embeds,
    float* __restrict__ out)
{
    const int tid = threadIdx.x;
    const int wave = tid >> 6, lane = tid & 63;
    const float sc = 1.0f / QSCALE;
    float s0[8], s1[8], s2[8], s3[8];
    #pragma unroll
    for (int j = 0; j < 8; j++) {
        s0[j] = (float)(long long)SQ[0 * 512 + lane * 8 + j] * sc;
        s1[j] = (float)(long long)SQ[1 * 512 + lane * 8 + j] * sc;
        s2[j] = (float)(long long)SQ[2 * 512 + lane * 8 + j] * sc;
        s3[j] = (float)(long long)SQ[3 * 512 + lane * 8 + j] * sc;
    }
    for (int r4 = 0; r4 < 4; r4++) {
        int b = blockIdx.x * 16 + wave * 4 + r4;
        const float4* te4 = reinterpret_cast<const float4*>(text_embeds + (size_t)b * D);
        float4 t0 = te4[lane * 2], t1 = te4[lane * 2 + 1];
        float te[8] = { t0.x, t0.y, t0.z, t0.w, t1.x, t1.y, t1.z, t1.w };
        float c0 = 0.f, c1 = 0.f, c2 = 0.f, c3 = 0.f;
        #pragma unroll
        for (int j = 0; j < 8; j++) {
            c0 += te[j] * s0[j];
            c1 += te[j] * s1[j];
            c2 += te[j] * s2[j];
            c3 += te[j] * s3[j];
        }
        for (int off = 32; off; off >>= 1) {
            c0 += __shfl_down(c0, off, 64);
            c1 += __shfl_down(c1, off, 64);
            c2 += __shfl_down(c2, off, 64);
            c3 += __shfl_down(c3, off, 64);
        }
        if (lane == 0) {
            float t0c = c0 + c2, t1c = c1 + c3;   // text_combine
            float v0c = c0 + c1, v1c = c2 + c3;   // vision_combine
            float tm = fmaxf(t0c, t1c);
            float te0 = expf(t0c - tm), te1 = expf(t1c - tm);
            float ts = te0 + te1;
            float mt0 = te0 / ts, mt1 = te1 / ts;
            float vm = fmaxf(v0c, v1c);
            float ve0 = expf(v0c - vm), ve1 = expf(v1c - vm);
            float vs = ve0 + ve1;
            float mv0 = ve0 / vs, mv1 = ve1 / vs;
            float4 o = { mt0 * mv0, mt1 * mv0, mt0 * mv1, mt1 * mv1 };
            *reinterpret_cast<float4*>(out + (size_t)b * 4) = o;
        }
    }
}

// ---------------------------------------------------------------------------
extern "C" void kernel_launch(void* const* d_in, const int* in_sizes, int n_in,
                              void* d_out, int out_size, void* d_ws, size_t ws_size,
                              hipStream_t stream)
{
    (void)in_sizes; (void)n_in; (void)out_size; (void)ws_size;
    const float* logits      = (const float*)d_in[0];
    const float* text_embeds = (const float*)d_in[1];
    const float* ent_memo    = (const float*)d_in[3];
    const float* text_memo   = (const float*)d_in[4];
    float* out = (float*)d_out;
    char* ws = (char*)d_ws;

    // workspace layout (bytes), 256-aligned
    int*   blockCnt = (int*)(ws + 0);                        // 256 B
    uint2* candList = (uint2*)(ws + 256);                    // 128 KB -> 131328
    unsigned long long* SQ   = (unsigned long long*)(ws + 131328); // 16 KB -> 147712
    unsigned long long* Tkey = (unsigned long long*)(ws + 147712); // 32 B

    k1_stats<<<NSEG, 256, 0, stream>>>(logits, ent_memo, out, blockCnt,
                                       candList, SQ);
    kT_select<<<1, 256, 0, stream>>>(blockCnt, candList, ent_memo, Tkey);
    kB_acc<<<576, 256, 0, stream>>>(blockCnt, candList, ent_memo, Tkey,
                                    text_memo, text_embeds, SQ);
    kC_cosin<<<1024, 256, 0, stream>>>(SQ, text_embeds, out);
}

// Round 14
// 73.009 us; speedup vs baseline: 5.2033x; 5.2033x over previous
//
#include <hip/hip_runtime.h>

#define B 16384
#define C 4
#define M 512
#define D 512
#define NSEG 64   // B/256 candidate segments
#define QSCALE 16777216.0f   // 2^24 fixed-point scale for deterministic atomics
#define BCAP 1024            // boundary-bin collection capacity

// normalize -0.0 -> +0.0 so positive-float bit ordering is valid
__device__ inline unsigned posbits(float e)
{
    unsigned b = __float_as_uint(e);
    return (b == 0x80000000u) ? 0u : b;
}
// monotone (non-strict) 8-bit bin of the entropy; ent in [0, ln4]
__device__ inline int binOfBits(unsigned bits)
{
    float e = __uint_as_float(bits);
    float s = fminf(fmaxf(e * 12000000.0f, 0.0f), 16777215.0f);
    return (int)((unsigned)s >> 16);
}

// ---------------- K0: zero the global histogram ---------------------------
__global__ void k0_zero(int* __restrict__ hist)
{
    int t = threadIdx.x;
    #pragma unroll
    for (int i = 0; i < 4; i++) hist[i * 256 + t] = 0;
}

// ---------------- K1: stats + candList + privatized histogram -------------
__global__ __launch_bounds__(256) void k1_stats(
    const float* __restrict__ logits,
    const float* __restrict__ ent_memo,
    float* __restrict__ out,
    int* __restrict__ blockCnt,
    uint2* __restrict__ candList,
    unsigned long long* __restrict__ SQ,
    int* __restrict__ hist)
{
    __shared__ int wscan[4];
    __shared__ int whist[4][1024];     // 16 KB, per-wave privatized [lab*256+bin]
    const int tid = threadIdx.x, blk = blockIdx.x;
    const int gid = blk * 256 + tid;
    const int lane = tid & 63, wv = tid >> 6;

    for (int i = tid; i < 4096; i += 256) ((int*)whist)[i] = 0;

    float4 l = *reinterpret_cast<const float4*>(logits + (size_t)gid * 4);
    float m = l.x; int idx = 0;
    if (l.y > m) { m = l.y; idx = 1; }
    if (l.z > m) { m = l.z; idx = 2; }
    if (l.w > m) { m = l.w; idx = 3; }
    float e0 = expf(l.x - m), e1 = expf(l.y - m), e2 = expf(l.z - m), e3 = expf(l.w - m);
    float s = e0 + e1 + e2 + e3;
    float inv = 1.0f / s;
    float p0 = e0 * inv, p1 = e1 * inv, p2 = e2 * inv, p3 = e3 * inv;
    float lse = logf(s);
    float ent = -(p0 * (l.x - m - lse) + p1 * (l.y - m - lse)
                + p2 * (l.z - m - lse) + p3 * (l.w - m - lse));
    float4 pr = { p0, p1, p2, p3 };
    *reinterpret_cast<float4*>(out + (size_t)B * 4 + (size_t)gid * 4) = pr;
    out[(size_t)B * 8 + gid] = ent;

    if (gid < C * M) SQ[gid] = 0ULL;

    float amax = ent_memo[(idx << 9) + M - 1];
    bool flag = ent < amax;
    unsigned bits = posbits(ent);
    __syncthreads();                   // whist zero-init complete

    if (flag) atomicAdd(&whist[wv][(idx << 8) | binOfBits(bits)], 1);
    if (blk < 8) {                     // memo rows ride on blocks 0..7
        unsigned mb = posbits(ent_memo[gid]);
        atomicAdd(&whist[wv][((gid >> 9) << 8) | binOfBits(mb)], 1);
    }

    // block-level compaction (order = b ascending within segment)
    unsigned long long mask = __ballot(flag);
    int prefix = __popcll(mask & ((1ull << lane) - 1ull));
    if (lane == 0) wscan[wv] = __popcll(mask);
    __syncthreads();
    int base = 0;
    for (int w = 0; w < wv; w++) base += wscan[w];
    if (flag)
        candList[blk * 256 + base + prefix] =
            make_uint2(bits, ((unsigned)idx << 14) | (unsigned)gid);
    if (tid == 0)
        blockCnt[blk] = wscan[0] + wscan[1] + wscan[2] + wscan[3];

    // merge privatized hists -> global (distinct addresses, low contention)
    for (int i = tid; i < 1024; i += 256) {
        int h = ((whist[0][i] + whist[1][i]) + whist[2][i]) + whist[3][i];
        if (h) atomicAdd(&hist[i], h);
    }
}

// ---------------- KB: per-block exact select + masked accumulate -> SQ -----
// blocks 0..511: batch, seg = x>>3, colchunk q = x&7 (64 cols).
// blocks 512..575: memo rowgroups. Deterministic int64 fixed-point atomics.
__global__ __launch_bounds__(256) void kB_acc(
    const int* __restrict__ blockCnt,
    const uint2* __restrict__ candList,
    const float* __restrict__ ent_memo,
    const int* __restrict__ hist,
    const float* __restrict__ text_memo,
    const float* __restrict__ text_embeds,
    unsigned long long* __restrict__ SQ)
{
    __shared__ int cnts[NSEG];
    __shared__ int hist_s[1024];
    __shared__ unsigned long long bkeys[BCAP]; // 8 KB
    __shared__ int blabs[BCAP];                // 4 KB
    __shared__ int bnum;
    __shared__ int betaS[4], mremS[4];
    __shared__ unsigned long long TkeyS[4];
    __shared__ int meta[256];

    const int x = blockIdx.x, tid = threadIdx.x;
    const int col0 = (x & 7) << 6;
    const int lane = tid & 63, sg = tid >> 6;

    // ---- select preamble (identical, deterministic, in every block) ----
    if (tid < NSEG) cnts[tid] = blockCnt[tid];
    for (int i = tid; i < 1024; i += 256) hist_s[i] = hist[i];
    if (tid == 0) bnum = 0;
    if (tid < 4) TkeyS[tid] = ~0ULL;
    __syncthreads();
    if (tid < 4) {
        int cum = 0, beta = 255, mr = M;
        for (int bin = 0; bin < 256; bin++) {
            int h = hist_s[(tid << 8) | bin];
            if (cum + h >= M) { beta = bin; mr = M - cum; break; }
            cum += h;
        }
        betaS[tid] = beta; mremS[tid] = mr;    // need mr-th smallest in bin beta
    }
    __syncthreads();
    for (int slot = tid; slot < B; slot += 256) {
        uint2 v = candList[slot];              // unconditional (allocated)
        if ((slot & 255) < cnts[slot >> 8]) {
            int lab = (int)((v.y >> 14) & 3);
            if (binOfBits(v.x) == betaS[lab]) {
                int id = atomicAdd(&bnum, 1);
                if (id < BCAP) {
                    bkeys[id] = ((unsigned long long)v.x << 15)
                              | (unsigned)(512 + (v.y & 0x3FFF));
                    blabs[id] = lab;
                }
            }
        }
    }
    for (int i = tid; i < C * M; i += 256) {
        unsigned bits = posbits(ent_memo[i]);
        int lab = i >> 9;
        if (binOfBits(bits) == betaS[lab]) {
            int id = atomicAdd(&bnum, 1);
            if (id < BCAP) {
                bkeys[id] = ((unsigned long long)bits << 15) | (unsigned)(i & (M - 1));
                blabs[id] = lab;
            }
        }
    }
    __syncthreads();
    int nb = bnum < BCAP ? bnum : BCAP;
    for (int t = tid; t < nb; t += 256) {
        unsigned long long k = bkeys[t]; int l = blabs[t];
        int r = 0;
        for (int j = 0; j < nb; j++)
            if (blabs[j] == l && bkeys[j] < k) r++;
        if (r == mremS[l] - 1) TkeyS[l] = k;   // unique winner per label
    }
    __syncthreads();

    // ---- masked dense accumulate (proven engine) ----
    if (x < 512) {
        const int seg = x >> 3;
        const int cnt = cnts[seg];
        {
            uint2 v = candList[(seg << 8) + tid];
            int lab = (int)((v.y >> 14) & 3);
            unsigned long long key = ((unsigned long long)v.x << 15)
                                   | (unsigned)(512 + (v.y & 0x3FFF));
            bool kept = (tid < cnt) && (key <= TkeyS[lab]);
            meta[tid] = kept ? (int)((unsigned)lab | 4u | ((v.y & 0x3FFF) << 3)) : 0;
        }
        __syncthreads();
        float a0 = 0.f, a1 = 0.f, a2 = 0.f, a3 = 0.f;
        #pragma unroll 8
        for (int k = 0; k < 64; k++) {
            int slot = (k << 2) | sg;               // wave-uniform
            int mt = meta[slot];
            int bidx = mt >> 3;
            float vv = text_embeds[(size_t)bidx * D + col0 + lane]; // unkept -> row 0 (L2)
            bool kept = (mt & 4) != 0;
            int lb = mt & 3;
            a0 += (kept && lb == 0) ? vv : 0.f;
            a1 += (kept && lb == 1) ? vv : 0.f;
            a2 += (kept && lb == 2) ? vv : 0.f;
            a3 += (kept && lb == 3) ? vv : 0.f;
        }
        __shared__ float red[4][4][64];             // [sg][label][lane]
        red[sg][0][lane] = a0; red[sg][1][lane] = a1;
        red[sg][2][lane] = a2; red[sg][3][lane] = a3;
        __syncthreads();
        float t = ((red[0][sg][lane] + red[1][sg][lane])
                 + red[2][sg][lane]) + red[3][sg][lane];
        long long q = llrintf(t * QSCALE);
        atomicAdd(&SQ[(sg << 9) + col0 + lane], (unsigned long long)q);
    } else {
        const int g = (x - 512) >> 3;               // rowgroup 0..7
        const int c = g >> 1;                       // label
        const int base = g << 8;                    // first global memo row
        {
            int i = base + tid;
            unsigned bits = posbits(ent_memo[i]);
            unsigned long long key = ((unsigned long long)bits << 15)
                                   | (unsigned)(i & (M - 1));
            meta[tid] = (key <= TkeyS[c]) ? 1 : 0;
        }
        __syncthreads();
        float a = 0.f;
        #pragma unroll 8
        for (int k = 0; k < 64; k++) {
            int slot = (k << 2) | sg;
            float vv = text_memo[(size_t)(base + slot) * D + col0 + lane];
            a += meta[slot] ? vv : 0.f;
        }
        __shared__ float redm[4][64];
        redm[sg][lane] = a;
        __syncthreads();
        if (tid < 64) {
            float t = ((redm[0][tid] + redm[1][tid]) + redm[2][tid]) + redm[3][tid];
            long long q = llrintf(t * QSCALE);
            atomicAdd(&SQ[(c << 9) + col0 + tid], (unsigned long long)q);
        }
    }
}

// ---------------- KC: SQ->VGPR S + GEMV + combines + softmaxes -------------
__global__ __launch_bounds__(256) void kC_cosin(
    const unsigned long long* __restrict__ SQ,
    const float* __restrict__ text_embeds,
    float* __restrict__ out)
{
    const int tid = threadIdx.x;
    const int wave = tid >> 6, lane = tid & 63;
    const float sc = 1.0f / QSCALE;
    float s0[8], s1[8], s2[8], s3[8];
    #pragma unroll
    for (int j = 0; j < 8; j++) {
        s0[j] = (float)(long long)SQ[0 * 512 + lane * 8 + j] * sc;
        s1[j] = (float)(long long)SQ[1 * 512 + lane * 8 + j] * sc;
        s2[j] = (float)(long long)SQ[2 * 512 + lane * 8 + j] * sc;
        s3[j] = (float)(long long)SQ[3 * 512 + lane * 8 + j] * sc;
    }
    for (int r4 = 0; r4 < 4; r4++) {
        int b = blockIdx.x * 16 + wave * 4 + r4;
        const float4* te4 = reinterpret_cast<const float4*>(text_embeds + (size_t)b * D);
        float4 t0 = te4[lane * 2], t1 = te4[lane * 2 + 1];
        float te[8] = { t0.x, t0.y, t0.z, t0.w, t1.x, t1.y, t1.z, t1.w };
        float c0 = 0.f, c1 = 0.f, c2 = 0.f, c3 = 0.f;
        #pragma unroll
        for (int j = 0; j < 8; j++) {
            c0 += te[j] * s0[j];
            c1 += te[j] * s1[j];
            c2 += te[j] * s2[j];
            c3 += te[j] * s3[j];
        }
        for (int off = 32; off; off >>= 1) {
            c0 += __shfl_down(c0, off, 64);
            c1 += __shfl_down(c1, off, 64);
            c2 += __shfl_down(c2, off, 64);
            c3 += __shfl_down(c3, off, 64);
        }
        if (lane == 0) {
            float t0c = c0 + c2, t1c = c1 + c3;   // text_combine
            float v0c = c0 + c1, v1c = c2 + c3;   // vision_combine
            float tm = fmaxf(t0c, t1c);
            float te0 = expf(t0c - tm), te1 = expf(t1c - tm);
            float ts = te0 + te1;
            float mt0 = te0 / ts, mt1 = te1 / ts;
            float vm = fmaxf(v0c, v1c);
            float ve0 = expf(v0c - vm), ve1 = expf(v1c - vm);
            float vs = ve0 + ve1;
            float mv0 = ve0 / vs, mv1 = ve1 / vs;
            float4 o = { mt0 * mv0, mt1 * mv0, mt0 * mv1, mt1 * mv1 };
            *reinterpret_cast<float4*>(out + (size_t)b * 4) = o;
        }
    }
}

// ---------------------------------------------------------------------------
extern "C" void kernel_launch(void* const* d_in, const int* in_sizes, int n_in,
                              void* d_out, int out_size, void* d_ws, size_t ws_size,
                              hipStream_t stream)
{
    (void)in_sizes; (void)n_in; (void)out_size; (void)ws_size;
    const float* logits      = (const float*)d_in[0];
    const float* text_embeds = (const float*)d_in[1];
    const float* ent_memo    = (const float*)d_in[3];
    const float* text_memo   = (const float*)d_in[4];
    float* out = (float*)d_out;
    char* ws = (char*)d_ws;

    // workspace layout (bytes), 256-aligned
    int*   blockCnt = (int*)(ws + 0);                        // 256 B
    uint2* candList = (uint2*)(ws + 256);                    // 128 KB -> 131328
    unsigned long long* SQ = (unsigned long long*)(ws + 131328); // 16 KB -> 147712
    int*   hist     = (int*)(ws + 147712);                   // 4 KB   -> 151808

    k0_zero<<<1, 256, 0, stream>>>(hist);
    k1_stats<<<NSEG, 256, 0, stream>>>(logits, ent_memo, out, blockCnt,
                                       candList, SQ, hist);
    kB_acc<<<576, 256, 0, stream>>>(blockCnt, candList, ent_memo, hist,
                                    text_memo, text_embeds, SQ);
    kC_cosin<<<1024, 256, 0, stream>>>(SQ, text_embeds, out);
}

// Round 15
// 51.851 us; speedup vs baseline: 7.3266x; 1.4081x over previous
//
#include <hip/hip_runtime.h>

#define B 16384
#define C 4
#define M 512
#define D 512
#define NCH 16
#define NSEG 64   // B/256 candidate segments
#define QSCALE 16777216.0f   // 2^24 fixed-point scale for deterministic atomics

// ---------------- K1: stats + segmented candidate build (no atomics) -------
__global__ __launch_bounds__(256) void k1_stats(
    const float* __restrict__ logits,
    const float* __restrict__ ent_memo,
    float* __restrict__ out,
    int* __restrict__ blockCnt,
    uint2* __restrict__ candList,
    int* __restrict__ rnkB,
    int* __restrict__ rnkM,
    unsigned long long* __restrict__ SQ)
{
    __shared__ int wscan[4];
    const int tid = threadIdx.x, blk = blockIdx.x;
    const int gid = blk * 256 + tid;

    float4 l = *reinterpret_cast<const float4*>(logits + (size_t)gid * 4);
    float m = l.x; int idx = 0;
    if (l.y > m) { m = l.y; idx = 1; }
    if (l.z > m) { m = l.z; idx = 2; }
    if (l.w > m) { m = l.w; idx = 3; }
    float e0 = expf(l.x - m), e1 = expf(l.y - m), e2 = expf(l.z - m), e3 = expf(l.w - m);
    float s = e0 + e1 + e2 + e3;
    float inv = 1.0f / s;
    float p0 = e0 * inv, p1 = e1 * inv, p2 = e2 * inv, p3 = e3 * inv;
    float lse = logf(s);
    float ent = -(p0 * (l.x - m - lse) + p1 * (l.y - m - lse)
                + p2 * (l.z - m - lse) + p3 * (l.w - m - lse));
    float4 pr = { p0, p1, p2, p3 };
    *reinterpret_cast<float4*>(out + (size_t)B * 4 + (size_t)gid * 4) = pr;
    out[(size_t)B * 8 + gid] = ent;

    rnkB[gid] = 0;
    if (gid < C * M) { rnkM[gid] = 0; SQ[gid] = 0ULL; }

    const float* Ac = ent_memo + (idx << 9);
    bool flag = ent < Ac[M - 1];
    unsigned lo = 0;
    if (flag) {
        int l0 = 0, hi = M;                  // upper_bound -> #{A <= ent}
        while (l0 < hi) { int mid = (l0 + hi) >> 1; if (Ac[mid] <= ent) l0 = mid + 1; else hi = mid; }
        lo = (unsigned)l0;
    }
    // block-level compaction (order = b ascending within segment)
    unsigned long long mask = __ballot(flag);
    int lane = tid & 63, wv = tid >> 6;
    int prefix = __popcll(mask & ((1ull << lane) - 1ull));
    if (lane == 0) wscan[wv] = __popcll(mask);
    __syncthreads();
    int base = 0;
    for (int w = 0; w < wv; w++) base += wscan[w];
    if (flag)
        candList[blk * 256 + base + prefix] =
            make_uint2(__float_as_uint(ent),
                       (lo << 16) | ((unsigned)idx << 14) | (unsigned)gid);
    if (tid == 0)
        blockCnt[blk] = wscan[0] + wscan[1] + wscan[2] + wscan[3];
}

// ---------------- K2a: pairwise stable-rank partial counts -----------------
// grid (NSEG+8, NCH): x<NSEG -> candidate-role block x; x>=NSEG -> memo rows.
__global__ __launch_bounds__(256) void k2a_count(
    const float* __restrict__ ent_memo,
    const int* __restrict__ blockCnt,
    const uint2* __restrict__ candList,
    int* __restrict__ rnkB,
    int* __restrict__ rnkM)
{
    __shared__ uint2 ch[1024];      // 4 candidate segments of this y-chunk
    const int x = blockIdx.x, y = blockIdx.y, tid = threadIdx.x;

    int s0 = blockCnt[4 * y + 0];
    int s1 = blockCnt[4 * y + 1];
    int s2 = blockCnt[4 * y + 2];
    int s3 = blockCnt[4 * y + 3];
    int o1 = s0, o2 = s0 + s1, o3 = o2 + s2, total = o3 + s3;
    for (int j = tid; j < s0; j += 256) ch[j]      = candList[(4 * y + 0) * 256 + j];
    for (int j = tid; j < s1; j += 256) ch[o1 + j] = candList[(4 * y + 1) * 256 + j];
    for (int j = tid; j < s2; j += 256) ch[o2 + j] = candList[(4 * y + 2) * 256 + j];
    for (int j = tid; j < s3; j += 256) ch[o3 + j] = candList[(4 * y + 3) * 256 + j];
    __syncthreads();

    if (x < NSEG) {
        if (tid < blockCnt[x]) {
            uint2 v = candList[x * 256 + tid];
            float e = __uint_as_float(v.x);
            int lab = (int)((v.y >> 14) & 3);
            int bidx = (int)(v.y & 0x3FFF);
            int r = 0;
            for (int i = 0; i < total; i++) {
                uint2 w = ch[i];
                float e2 = __uint_as_float(w.x);
                if ((int)((w.y >> 14) & 3) == lab &&
                    (e2 < e || (e2 == e && (int)(w.y & 0x3FFF) < bidx))) r++;
            }
            if (r) atomicAdd(&rnkB[x * 256 + tid], r);
        }
    } else {
        int t = (x - NSEG) * 256 + tid;       // [0, C*M)
        float Am = ent_memo[t];
        int mc = t >> 9;
        int rm = 0;
        for (int i = 0; i < total; i++) {
            uint2 w = ch[i];
            if ((int)((w.y >> 14) & 3) == mc && __uint_as_float(w.x) < Am) rm++;
        }
        if (rm) atomicAdd(&rnkM[t], rm);
    }
}

// ---------------- K4acc: flag-masked dense accumulate -> SQ (int64 fx) -----
// blocks 0..511: batch, seg = x>>3, colchunk q = x&7 (64 cols).
// blocks 512..575: memo, rowgroup g = (x-512)>>3 (256 rows, one label), q.
// Deterministic: per-block fp32 partials (fixed order) -> one int64 atomicAdd.
// Inner loops use explicit 8-wide prefetch batches to keep 8 loads in flight.
__global__ __launch_bounds__(256) void k4acc(
    const int* __restrict__ blockCnt,
    const uint2* __restrict__ candList,
    const int* __restrict__ rnkB,
    const int* __restrict__ rnkM,
    const float* __restrict__ text_memo,
    const float* __restrict__ text_embeds,
    unsigned long long* __restrict__ SQ)
{
    __shared__ int meta[256];
    const int x = blockIdx.x, tid = threadIdx.x;
    const int col0 = (x & 7) << 6;             // q*64
    const int lane = tid & 63, sg = tid >> 6;  // 4 slot-groups (waves)

    if (x < 512) {
        const int seg = x >> 3;
        {
            int cnt = blockCnt[seg];
            uint2 v = candList[(seg << 8) + tid];   // unconditional (allocated)
            int rb = rnkB[(seg << 8) + tid];        // unconditional (zeroed)
            bool kept = (tid < cnt) && ((int)(v.y >> 16) + rb < M);
            meta[tid] = kept ? (int)(((v.y >> 14) & 3) | 4u | ((v.y & 0x3FFF) << 3)) : 0;
        }
        __syncthreads();
        float a0 = 0.f, a1 = 0.f, a2 = 0.f, a3 = 0.f;
        #pragma unroll
        for (int kb = 0; kb < 8; kb++) {
            int mt0_ = meta[(((kb << 3) | 0) << 2) | sg];
            int mt1_ = meta[(((kb << 3) | 1) << 2) | sg];
            int mt2_ = meta[(((kb << 3) | 2) << 2) | sg];
            int mt3_ = meta[(((kb << 3) | 3) << 2) | sg];
            int mt4_ = meta[(((kb << 3) | 4) << 2) | sg];
            int mt5_ = meta[(((kb << 3) | 5) << 2) | sg];
            int mt6_ = meta[(((kb << 3) | 6) << 2) | sg];
            int mt7_ = meta[(((kb << 3) | 7) << 2) | sg];
            float v0_ = text_embeds[(size_t)(mt0_ >> 3) * D + col0 + lane];
            float v1_ = text_embeds[(size_t)(mt1_ >> 3) * D + col0 + lane];
            float v2_ = text_embeds[(size_t)(mt2_ >> 3) * D + col0 + lane];
            float v3_ = text_embeds[(size_t)(mt3_ >> 3) * D + col0 + lane];
            float v4_ = text_embeds[(size_t)(mt4_ >> 3) * D + col0 + lane];
            float v5_ = text_embeds[(size_t)(mt5_ >> 3) * D + col0 + lane];
            float v6_ = text_embeds[(size_t)(mt6_ >> 3) * D + col0 + lane];
            float v7_ = text_embeds[(size_t)(mt7_ >> 3) * D + col0 + lane];
            int mts[8] = { mt0_, mt1_, mt2_, mt3_, mt4_, mt5_, mt6_, mt7_ };
            float vvs[8] = { v0_, v1_, v2_, v3_, v4_, v5_, v6_, v7_ };
            #pragma unroll
            for (int u = 0; u < 8; u++) {
                bool kept = (mts[u] & 4) != 0;
                int lb = mts[u] & 3;
                float vv = vvs[u];
                a0 += (kept && lb == 0) ? vv : 0.f;
                a1 += (kept && lb == 1) ? vv : 0.f;
                a2 += (kept && lb == 2) ? vv : 0.f;
                a3 += (kept && lb == 3) ? vv : 0.f;
            }
        }
        __shared__ float red[4][4][64];             // [sg][label][lane]
        red[sg][0][lane] = a0; red[sg][1][lane] = a1;
        red[sg][2][lane] = a2; red[sg][3][lane] = a3;
        __syncthreads();
        // thread (sg=label, lane=col): fixed-order sum over the 4 slot-groups
        float t = ((red[0][sg][lane] + red[1][sg][lane])
                 + red[2][sg][lane]) + red[3][sg][lane];
        long long q = llrintf(t * QSCALE);
        atomicAdd(&SQ[(sg << 9) + col0 + lane], (unsigned long long)q);
    } else {
        const int g = (x - 512) >> 3;               // rowgroup 0..7
        const int c = g >> 1;                       // label
        const int base = g << 8;                    // first global memo row
        {
            int i = base + tid;
            meta[tid] = ((i & (M - 1)) + rnkM[i] < M) ? 1 : 0;
        }
        __syncthreads();
        float a = 0.f;
        #pragma unroll
        for (int kb = 0; kb < 8; kb++) {
            // addresses independent of meta -> loads pipeline freely
            float v0_ = text_memo[(size_t)(base + ((((kb << 3) | 0) << 2) | sg)) * D + col0 + lane];
            float v1_ = text_memo[(size_t)(base + ((((kb << 3) | 1) << 2) | sg)) * D + col0 + lane];
            float v2_ = text_memo[(size_t)(base + ((((kb << 3) | 2) << 2) | sg)) * D + col0 + lane];
            float v3_ = text_memo[(size_t)(base + ((((kb << 3) | 3) << 2) | sg)) * D + col0 + lane];
            float v4_ = text_memo[(size_t)(base + ((((kb << 3) | 4) << 2) | sg)) * D + col0 + lane];
            float v5_ = text_memo[(size_t)(base + ((((kb << 3) | 5) << 2) | sg)) * D + col0 + lane];
            float v6_ = text_memo[(size_t)(base + ((((kb << 3) | 6) << 2) | sg)) * D + col0 + lane];
            float v7_ = text_memo[(size_t)(base + ((((kb << 3) | 7) << 2) | sg)) * D + col0 + lane];
            a += meta[(((kb << 3) | 0) << 2) | sg] ? v0_ : 0.f;
            a += meta[(((kb << 3) | 1) << 2) | sg] ? v1_ : 0.f;
            a += meta[(((kb << 3) | 2) << 2) | sg] ? v2_ : 0.f;
            a += meta[(((kb << 3) | 3) << 2) | sg] ? v3_ : 0.f;
            a += meta[(((kb << 3) | 4) << 2) | sg] ? v4_ : 0.f;
            a += meta[(((kb << 3) | 5) << 2) | sg] ? v5_ : 0.f;
            a += meta[(((kb << 3) | 6) << 2) | sg] ? v6_ : 0.f;
            a += meta[(((kb << 3) | 7) << 2) | sg] ? v7_ : 0.f;
        }
        __shared__ float redm[4][64];
        redm[sg][lane] = a;
        __syncthreads();
        if (tid < 64) {
            float t = ((redm[0][tid] + redm[1][tid]) + redm[2][tid]) + redm[3][tid];
            long long q = llrintf(t * QSCALE);
            atomicAdd(&SQ[(c << 9) + col0 + tid], (unsigned long long)q);
        }
    }
}

// ---------------- K5: SQ->VGPR S + GEMV + combines + softmaxes -------------
// 1024 blocks x 256 thr (proven shape: 4 blocks/CU), 4 rows per wave.
__global__ __launch_bounds__(256) void k5_cosin(
    const unsigned long long* __restrict__ SQ,
    const float* __restrict__ text_embeds,
    float* __restrict__ out)
{
    const int tid = threadIdx.x;
    const int wave = tid >> 6, lane = tid & 63;
    const float sc = 1.0f / QSCALE;
    float s0[8], s1[8], s2[8], s3[8];
    #pragma unroll
    for (int j = 0; j < 8; j++) {
        s0[j] = (float)(long long)SQ[0 * 512 + lane * 8 + j] * sc;
        s1[j] = (float)(long long)SQ[1 * 512 + lane * 8 + j] * sc;
        s2[j] = (float)(long long)SQ[2 * 512 + lane * 8 + j] * sc;
        s3[j] = (float)(long long)SQ[3 * 512 + lane * 8 + j] * sc;
    }
    for (int r4 = 0; r4 < 4; r4++) {
        int b = blockIdx.x * 16 + wave * 4 + r4;
        const float4* te4 = reinterpret_cast<const float4*>(text_embeds + (size_t)b * D);
        float4 t0 = te4[lane * 2], t1 = te4[lane * 2 + 1];
        float te[8] = { t0.x, t0.y, t0.z, t0.w, t1.x, t1.y, t1.z, t1.w };
        float c0 = 0.f, c1 = 0.f, c2 = 0.f, c3 = 0.f;
        #pragma unroll
        for (int j = 0; j < 8; j++) {
            c0 += te[j] * s0[j];
            c1 += te[j] * s1[j];
            c2 += te[j] * s2[j];
            c3 += te[j] * s3[j];
        }
        for (int off = 32; off; off >>= 1) {
            c0 += __shfl_down(c0, off, 64);
            c1 += __shfl_down(c1, off, 64);
            c2 += __shfl_down(c2, off, 64);
            c3 += __shfl_down(c3, off, 64);
        }
        if (lane == 0) {
            float t0c = c0 + c2, t1c = c1 + c3;   // text_combine
            float v0c = c0 + c1, v1c = c2 + c3;   // vision_combine
            float tm = fmaxf(t0c, t1c);
            float te0 = expf(t0c - tm), te1 = expf(t1c - tm);
            float ts = te0 + te1;
            float mt0 = te0 / ts, mt1 = te1 / ts;
            float vm = fmaxf(v0c, v1c);
            float ve0 = expf(v0c - vm), ve1 = expf(v1c - vm);
            float vs = ve0 + ve1;
            float mv0 = ve0 / vs, mv1 = ve1 / vs;
            float4 o = { mt0 * mv0, mt1 * mv0, mt0 * mv1, mt1 * mv1 };
            *reinterpret_cast<float4*>(out + (size_t)b * 4) = o;
        }
    }
}

// ---------------------------------------------------------------------------
extern "C" void kernel_launch(void* const* d_in, const int* in_sizes, int n_in,
                              void* d_out, int out_size, void* d_ws, size_t ws_size,
                              hipStream_t stream)
{
    (void)in_sizes; (void)n_in; (void)out_size; (void)ws_size;
    const float* logits      = (const float*)d_in[0];
    const float* text_embeds = (const float*)d_in[1];
    const float* ent_memo    = (const float*)d_in[3];
    const float* text_memo   = (const float*)d_in[4];
    float* out = (float*)d_out;
    char* ws = (char*)d_ws;

    // workspace layout (bytes), 256-aligned
    int*   blockCnt = (int*)(ws + 0);                        // 256 B
    uint2* candList = (uint2*)(ws + 256);                    // 128 KB -> 131328
    int*   rnkB     = (int*)(ws + 131328);                   // 64 KB  -> 196864
    int*   rnkM     = (int*)(ws + 196864);                   // 8 KB   -> 205056
    unsigned long long* SQ = (unsigned long long*)(ws + 205056); // 16 KB -> 221440

    k1_stats<<<NSEG, 256, 0, stream>>>(logits, ent_memo, out, blockCnt,
                                       candList, rnkB, rnkM, SQ);
    k2a_count<<<dim3(NSEG + 8, NCH), 256, 0, stream>>>(ent_memo, blockCnt,
                                                       candList, rnkB, rnkM);
    k4acc<<<576, 256, 0, stream>>>(blockCnt, candList, rnkB, rnkM,
                                   text_memo, text_embeds, SQ);
    k5_cosin<<<1024, 256, 0, stream>>>(SQ, text_embeds, out);
}